// Round 2
// baseline (243.658 us; speedup 1.0000x reference)
//
#include <hip/hip_runtime.h>

// Node_GCN: out[n,j,h] = FF_f(x)[n,j,h] + sum_i edge[n,i,j] * FF_g(cat(x,x))[n,i,h]
// All global tensors fp32 (reference is jnp.float32). Internal math bf16 MFMA
// (threshold = 2% of ref absmax = 9.56 absolute -> bf16 rounding is safe).
// N=8, m=2048, D_IN=64, H=128, Hhid_f=64.
//
//   k_self : out[16384][128]   = relu(x@fw1+b)@fw2+b        (fp32 store, later RMW'd)
//   k_gx   : gxT[8][128][2048] = (relu(x@gw1'+b)@gw2+b)^T   (bf16 ws; gw1' = gw1[:64]+gw1[64:])
//   k_einsum: out += edge^T @ gx   per batch (A=edgeT via LDS transpose+cvt, B=gxT k-contig)

typedef __attribute__((ext_vector_type(8))) short bf16x8;
typedef __attribute__((ext_vector_type(8))) unsigned short u16x8;
typedef __attribute__((ext_vector_type(4))) unsigned short u16x4;
typedef __attribute__((ext_vector_type(4))) float f32x4;

static __device__ __forceinline__ unsigned short f2bf(float f) {
  union { float f; unsigned int i; } c; c.f = f;
  return (unsigned short)((c.i + 0x7fffu + ((c.i >> 16) & 1u)) >> 16);
}

// ---------------- k_self: self dynamics MLP (64 rows/block, 4 waves) ----------------
__global__ __launch_bounds__(256) void k_self(
    const float* __restrict__ x,
    const float* __restrict__ fw1,
    const float* __restrict__ fb1,
    const float* __restrict__ fw2,
    const float* __restrict__ fb2,
    float* __restrict__ out)
{
  // XOR-tight LDS layouts: elem(row,k) at row*W + ((k>>3)^(row&7))*8 + (k&7); W=64
  __shared__ short xs[64 * 64];    // 8 KB
  __shared__ short w1T[64 * 64];   // 8 KB   fw1T[n][k], k<64
  __shared__ short w2T[128 * 64];  // 16 KB  fw2T[n][k], k<64
  __shared__ short h1s[64 * 64];   // 8 KB

  const int t = threadIdx.x;
  const int R0 = blockIdx.x * 64;

  for (int idx = t; idx < 64 * 64; idx += 256) {
    int k = idx >> 6, n = idx & 63;  // fw1[k][n]
    w1T[(n << 6) + (((k >> 3) ^ (n & 7)) << 3) + (k & 7)] = (short)f2bf(fw1[idx]);
  }
  for (int idx = t; idx < 64 * 128; idx += 256) {
    int k = idx >> 7, n = idx & 127;  // fw2[k][n]
    w2T[(n << 6) + (((k >> 3) ^ (n & 7)) << 3) + (k & 7)] = (short)f2bf(fw2[idx]);
  }
  for (int s = t; s < 64 * 16; s += 256) {
    int row = s >> 4, c4 = s & 15;  // 16 float4 per 64-col row
    f32x4 v = *(const f32x4*)(x + (size_t)(R0 + row) * 64 + c4 * 4);
    u16x4 pk;
#pragma unroll
    for (int r = 0; r < 4; ++r) pk[r] = f2bf(v[r]);
    *(u16x4*)(xs + (row << 6) + (((c4 >> 1) ^ (row & 7)) << 3) + ((c4 & 1) << 2)) = pk;
  }
  __syncthreads();

  const int w = t >> 6, l = t & 63;
  const int lr = l & 15, q = l >> 4;
  const int mrow = w * 16 + lr;

  bf16x8 a[2];
#pragma unroll
  for (int ks = 0; ks < 2; ++ks) {
    int c = ks * 4 + q;
    a[ks] = *(const bf16x8*)(xs + (mrow << 6) + ((c ^ (mrow & 7)) << 3));
  }

  f32x4 acc;
#pragma unroll
  for (int nf = 0; nf < 4; ++nf) {
    acc = (f32x4){0.f, 0.f, 0.f, 0.f};
#pragma unroll
    for (int ks = 0; ks < 2; ++ks) {
      int c = ks * 4 + q;
      int nr = nf * 16 + lr;
      bf16x8 b = *(const bf16x8*)(w1T + (nr << 6) + ((c ^ (nr & 7)) << 3));
      acc = __builtin_amdgcn_mfma_f32_16x16x32_bf16(a[ks], b, acc, 0, 0, 0);
    }
    float bias = fb1[nf * 16 + lr];
#pragma unroll
    for (int r = 0; r < 4; ++r) {
      float v = acc[r] + bias;
      v = v > 0.f ? v : 0.f;
      int row = w * 16 + q * 4 + r, n = nf * 16 + lr;
      h1s[(row << 6) + (((n >> 3) ^ (row & 7)) << 3) + (n & 7)] = (short)f2bf(v);
    }
  }
  __syncthreads();

  bf16x8 a2[2];
#pragma unroll
  for (int ks = 0; ks < 2; ++ks) {
    int c = ks * 4 + q;
    a2[ks] = *(const bf16x8*)(h1s + (mrow << 6) + ((c ^ (mrow & 7)) << 3));
  }
#pragma unroll
  for (int nf = 0; nf < 8; ++nf) {
    acc = (f32x4){0.f, 0.f, 0.f, 0.f};
#pragma unroll
    for (int ks = 0; ks < 2; ++ks) {
      int c = ks * 4 + q;
      int nr = nf * 16 + lr;
      bf16x8 b = *(const bf16x8*)(w2T + (nr << 6) + ((c ^ (nr & 7)) << 3));
      acc = __builtin_amdgcn_mfma_f32_16x16x32_bf16(a2[ks], b, acc, 0, 0, 0);
    }
    float bias = fb2[nf * 16 + lr];
#pragma unroll
    for (int r = 0; r < 4; ++r)
      out[(size_t)(R0 + w * 16 + q * 4 + r) * 128 + nf * 16 + lr] = acc[r] + bias;
  }
}

// ---------------- k_gx: sender MLP, transposed bf16 store (64 rows/block, 4 waves) ----------------
__global__ __launch_bounds__(256) void k_gx(
    const float* __restrict__ x,
    const float* __restrict__ gw1,
    const float* __restrict__ gb1,
    const float* __restrict__ gw2,
    const float* __restrict__ gb2,
    unsigned short* __restrict__ gxT)
{
  __shared__ short xs[64 * 64];     // 8 KB
  __shared__ short w1T[128 * 64];   // 16 KB  folded gw1' transposed [n][k], k<64
  __shared__ short w2T[128 * 128];  // 32 KB  gw2T [n][k], k<128
  __shared__ short h2s[64 * 128];   // 16 KB  -> 72 KB total

  const int t = threadIdx.x;
  const int R0 = blockIdx.x * 64;

  for (int idx = t; idx < 64 * 128; idx += 256) {
    int k = idx >> 7, n = idx & 127;  // gw1[k][n], fold cat(x,x): +gw1[k+64][n]
    float v = gw1[idx] + gw1[64 * 128 + idx];
    w1T[(n << 6) + (((k >> 3) ^ (n & 7)) << 3) + (k & 7)] = (short)f2bf(v);
  }
  for (int idx = t; idx < 128 * 128; idx += 256) {
    int k = idx >> 7, n = idx & 127;  // gw2[k][n]
    w2T[(n << 7) + (((k >> 3) ^ (n & 7)) << 3) + (k & 7)] = (short)f2bf(gw2[idx]);
  }
  for (int s = t; s < 64 * 16; s += 256) {
    int row = s >> 4, c4 = s & 15;
    f32x4 v = *(const f32x4*)(x + (size_t)(R0 + row) * 64 + c4 * 4);
    u16x4 pk;
#pragma unroll
    for (int r = 0; r < 4; ++r) pk[r] = f2bf(v[r]);
    *(u16x4*)(xs + (row << 6) + (((c4 >> 1) ^ (row & 7)) << 3) + ((c4 & 1) << 2)) = pk;
  }
  __syncthreads();

  const int w = t >> 6, l = t & 63;
  const int lr = l & 15, q = l >> 4;
  const int mrow = w * 16 + lr;

  bf16x8 a[2];
#pragma unroll
  for (int ks = 0; ks < 2; ++ks) {
    int c = ks * 4 + q;
    a[ks] = *(const bf16x8*)(xs + (mrow << 6) + ((c ^ (mrow & 7)) << 3));
  }

  f32x4 acc;
#pragma unroll
  for (int nf = 0; nf < 8; ++nf) {
    acc = (f32x4){0.f, 0.f, 0.f, 0.f};
#pragma unroll
    for (int ks = 0; ks < 2; ++ks) {
      int c = ks * 4 + q;
      int nr = nf * 16 + lr;
      bf16x8 b = *(const bf16x8*)(w1T + (nr << 6) + ((c ^ (nr & 7)) << 3));
      acc = __builtin_amdgcn_mfma_f32_16x16x32_bf16(a[ks], b, acc, 0, 0, 0);
    }
    float bias = gb1[nf * 16 + lr];
#pragma unroll
    for (int r = 0; r < 4; ++r) {
      float v = acc[r] + bias;
      v = v > 0.f ? v : 0.f;
      int row = w * 16 + q * 4 + r, n = nf * 16 + lr;
      h2s[(row << 7) + (((n >> 3) ^ (row & 7)) << 3) + (n & 7)] = (short)f2bf(v);
    }
  }
  __syncthreads();

  bf16x8 a2[4];
#pragma unroll
  for (int ks = 0; ks < 4; ++ks) {
    int c = ks * 4 + q;  // c in [0,16); XOR flips low 3 bits only
    a2[ks] = *(const bf16x8*)(h2s + (mrow << 7) + ((c ^ (mrow & 7)) << 3));
  }
  const int batch = R0 >> 11;
  const int ib = R0 & 2047;
#pragma unroll
  for (int nf = 0; nf < 8; ++nf) {
    acc = (f32x4){0.f, 0.f, 0.f, 0.f};
#pragma unroll
    for (int ks = 0; ks < 4; ++ks) {
      int c = ks * 4 + q;
      int nr = nf * 16 + lr;
      bf16x8 b = *(const bf16x8*)(w2T + (nr << 7) + ((c ^ (nr & 7)) << 3));
      acc = __builtin_amdgcn_mfma_f32_16x16x32_bf16(a2[ks], b, acc, 0, 0, 0);
    }
    float bias = gb2[nf * 16 + lr];
    u16x4 pk;
#pragma unroll
    for (int r = 0; r < 4; ++r) pk[r] = f2bf(acc[r] + bias);
    // transposed store: gxT[batch][h][i], 4 consecutive i per lane (8B)
    *(u16x4*)(gxT + (size_t)(batch * 128 + nf * 16 + lr) * 2048 + ib + w * 16 + q * 4) = pk;
  }
}

// ---------------- k_einsum: out[n,j,h] += sum_i edge[n,i,j]*gx[n,i,h] ----------------
typedef __attribute__((ext_vector_type(8))) float f32x8;

__device__ __forceinline__ void load_tiles(const float* eb, const unsigned short* gb,
                                           int i0, int j0, int e_ii, int e_cj,
                                           f32x8 er[2], u16x8 gr[4])
{
  er[0] = *(const f32x8*)(eb + (size_t)(i0 + e_ii) * 2048 + j0 + e_cj * 8);
  er[1] = *(const f32x8*)(eb + (size_t)(i0 + e_ii + 32) * 2048 + j0 + e_cj * 8);
#pragma unroll
  for (int qq = 0; qq < 4; ++qq)
    gr[qq] = *(const u16x8*)(gb + (size_t)(qq * 32 + e_ii) * 2048 + i0 + e_cj * 8);
}

__global__ __launch_bounds__(256) void k_einsum(
    const float* __restrict__ edge,
    const unsigned short* __restrict__ gxT,
    float* __restrict__ out)
{
  // eT[jj][ii]: padded stride 72 elems (144B) + XOR(jj>>3) on 16B chunks:
  //   addr = jj*72 + (((ii>>3) ^ (jj>>3))<<3) + (ii&7)
  // bT[h][ii]: tight 64 + XOR(h&7): addr = h*64 + (((ii>>3) ^ (h&7))<<3) + (ii&7)
  __shared__ short eT[64 * 72];   // 9 KB
  __shared__ short bT[128 * 64];  // 16 KB

  const int t = threadIdx.x;
  const int batch = blockIdx.x & 7;   // consecutive blocks -> different XCDs; each XCD sees one batch's gx (512KB, L2-resident)
  const int jt = blockIdx.x >> 3;
  const int j0 = jt * 64;

  const int w = t >> 6, l = t & 63;
  const int wm = w & 1, wn = w >> 1;
  const int lr = l & 15, q = l >> 4;

  const float* eb = edge + (size_t)batch * 2048 * 2048;
  const unsigned short* gb = gxT + (size_t)batch * 128 * 2048;

  const int e_ii = t >> 3;  // 0..31
  const int e_cj = t & 7;

  f32x4 acc[2][4];
#pragma unroll
  for (int f = 0; f < 2; ++f)
#pragma unroll
    for (int nf = 0; nf < 4; ++nf) acc[f][nf] = (f32x4){0.f, 0.f, 0.f, 0.f};

  f32x8 er[2];
  u16x8 gr[4];
  load_tiles(eb, gb, 0, j0, e_ii, e_cj, er, gr);

  for (int kk = 0; kk < 32; ++kk) {
    __syncthreads();  // previous iter's LDS reads complete
    // edge transpose-store with fp32->bf16 convert (8 elems per held row chunk)
#pragma unroll
    for (int rr = 0; rr < 2; ++rr) {
      int ii = e_ii + rr * 32;
#pragma unroll
      for (int u = 0; u < 8; ++u)
        eT[(e_cj * 8 + u) * 72 + (((ii >> 3) ^ e_cj) << 3) + (ii & 7)] = (short)f2bf(er[rr][u]);
    }
#pragma unroll
    for (int qq = 0; qq < 4; ++qq) {
      int r = qq * 32 + e_ii;
      *(u16x8*)(bT + (r << 6) + ((e_cj ^ (r & 7)) << 3)) = gr[qq];
    }
    __syncthreads();
    if (kk < 31) load_tiles(eb, gb, (kk + 1) * 64, j0, e_ii, e_cj, er, gr);  // prefetch overlaps MFMA

#pragma unroll
    for (int ks = 0; ks < 2; ++ks) {
      bf16x8 a[2], b[4];
#pragma unroll
      for (int f = 0; f < 2; ++f) {
        int jj = wm * 32 + f * 16 + lr;
        int c = ks * 4 + q;
        a[f] = *(const bf16x8*)(eT + jj * 72 + ((c ^ (jj >> 3)) << 3));
      }
#pragma unroll
      for (int nf = 0; nf < 4; ++nf) {
        int h = wn * 64 + nf * 16 + lr;
        int c = ks * 4 + q;
        b[nf] = *(const bf16x8*)(bT + (h << 6) + ((c ^ (h & 7)) << 3));
      }
#pragma unroll
      for (int f = 0; f < 2; ++f)
#pragma unroll
        for (int nf = 0; nf < 4; ++nf)
          acc[f][nf] = __builtin_amdgcn_mfma_f32_16x16x32_bf16(a[f], b[nf], acc[f][nf], 0, 0, 0);
    }
  }

  // epilogue: out += acc (out already holds self_dyn from k_self)
  const size_t rowbase = (size_t)batch * 2048 + j0 + wm * 32;
#pragma unroll
  for (int f = 0; f < 2; ++f) {
#pragma unroll
    for (int nf = 0; nf < 4; ++nf) {
      int h = wn * 64 + nf * 16 + lr;
#pragma unroll
      for (int r = 0; r < 4; ++r) {
        size_t o = (rowbase + f * 16 + q * 4 + r) * 128 + h;
        out[o] = acc[f][nf][r] + out[o];
      }
    }
  }
}

extern "C" void kernel_launch(void* const* d_in, const int* in_sizes, int n_in,
                              void* d_out, int out_size, void* d_ws, size_t ws_size,
                              hipStream_t stream) {
  const float* x    = (const float*)d_in[0];
  const float* edge = (const float*)d_in[1];
  const float* fw1  = (const float*)d_in[2];
  const float* fb1  = (const float*)d_in[3];
  const float* fw2  = (const float*)d_in[4];
  const float* fb2  = (const float*)d_in[5];
  const float* gw1  = (const float*)d_in[6];
  const float* gb1  = (const float*)d_in[7];
  const float* gw2  = (const float*)d_in[8];
  const float* gb2  = (const float*)d_in[9];
  float* out = (float*)d_out;

  unsigned short* gxT = (unsigned short*)d_ws;  // [8][128][2048] bf16, 4 MB

  hipLaunchKernelGGL(k_self, dim3(256), dim3(256), 0, stream, x, fw1, fb1, fw2, fb2, out);
  hipLaunchKernelGGL(k_gx, dim3(256), dim3(256), 0, stream, x, gw1, gb1, gw2, gb2, gxT);
  hipLaunchKernelGGL(k_einsum, dim3(256), dim3(256), 0, stream, edge, gxT, out);
}

// Round 3
// 239.590 us; speedup vs baseline: 1.0170x; 1.0170x over previous
//
#include <hip/hip_runtime.h>

// Node_GCN: out[n,j,h] = FF_f(x)[n,j,h] + sum_i edge[n,i,j] * FF_g(cat(x,x))[n,i,h]
// fp32 globals, bf16 MFMA internals (abs threshold 9.56 >> bf16 error ~2).
// N=8, m=2048, D_IN=64, H=128.
//
//   k_gx  : gxT[8][128][2048] bf16 = (relu(x@gw1'+b)@gw2+b)^T  (gw1' = gw1[:64]+gw1[64:])
//   k_main: out[n,j,h] = edge^T @ gx + self_MLP(x_j)   fused, pure store (no RMW)
//           512 blocks (2/CU): tile 32j x 128h, K=2048 in BK=64 steps.

typedef __attribute__((ext_vector_type(8))) short bf16x8;
typedef __attribute__((ext_vector_type(8))) unsigned short u16x8;
typedef __attribute__((ext_vector_type(4))) unsigned short u16x4;
typedef __attribute__((ext_vector_type(4))) float f32x4;
typedef __attribute__((ext_vector_type(8))) float f32x8;

static __device__ __forceinline__ unsigned short f2bf(float f) {
  union { float f; unsigned int i; } c; c.f = f;
  return (unsigned short)((c.i + 0x7fffu + ((c.i >> 16) & 1u)) >> 16);
}

// ---------------- k_gx: sender MLP, transposed bf16 store (64 rows/block, 4 waves) ----------------
__global__ __launch_bounds__(256) void k_gx(
    const float* __restrict__ x,
    const float* __restrict__ gw1,
    const float* __restrict__ gb1,
    const float* __restrict__ gw2,
    const float* __restrict__ gb2,
    unsigned short* __restrict__ gxT)
{
  __shared__ short xs[64 * 64];     // 8 KB
  __shared__ short w1T[128 * 64];   // 16 KB  folded gw1' transposed [n][k], k<64
  __shared__ short w2T[128 * 128];  // 32 KB  gw2T [n][k], k<128
  __shared__ short h2s[64 * 128];   // 16 KB

  const int t = threadIdx.x;
  const int R0 = blockIdx.x * 64;

  for (int idx = t; idx < 64 * 128; idx += 256) {
    int k = idx >> 7, n = idx & 127;  // gw1[k][n], fold cat(x,x): +gw1[k+64][n]
    float v = gw1[idx] + gw1[64 * 128 + idx];
    w1T[(n << 6) + (((k >> 3) ^ (n & 7)) << 3) + (k & 7)] = (short)f2bf(v);
  }
  for (int idx = t; idx < 128 * 128; idx += 256) {
    int k = idx >> 7, n = idx & 127;  // gw2[k][n]
    w2T[(n << 7) + (((k >> 3) ^ (n & 7)) << 3) + (k & 7)] = (short)f2bf(gw2[idx]);
  }
  for (int s = t; s < 64 * 16; s += 256) {
    int row = s >> 4, c4 = s & 15;
    f32x4 v = *(const f32x4*)(x + (size_t)(R0 + row) * 64 + c4 * 4);
    u16x4 pk;
#pragma unroll
    for (int r = 0; r < 4; ++r) pk[r] = f2bf(v[r]);
    *(u16x4*)(xs + (row << 6) + (((c4 >> 1) ^ (row & 7)) << 3) + ((c4 & 1) << 2)) = pk;
  }
  __syncthreads();

  const int w = t >> 6, l = t & 63;
  const int lr = l & 15, q = l >> 4;
  const int mrow = w * 16 + lr;

  bf16x8 a[2];
#pragma unroll
  for (int ks = 0; ks < 2; ++ks) {
    int c = ks * 4 + q;
    a[ks] = *(const bf16x8*)(xs + (mrow << 6) + ((c ^ (mrow & 7)) << 3));
  }

  f32x4 acc;
#pragma unroll
  for (int nf = 0; nf < 8; ++nf) {
    acc = (f32x4){0.f, 0.f, 0.f, 0.f};
#pragma unroll
    for (int ks = 0; ks < 2; ++ks) {
      int c = ks * 4 + q;
      int nr = nf * 16 + lr;
      bf16x8 b = *(const bf16x8*)(w1T + (nr << 6) + ((c ^ (nr & 7)) << 3));
      acc = __builtin_amdgcn_mfma_f32_16x16x32_bf16(a[ks], b, acc, 0, 0, 0);
    }
    float bias = gb1[nf * 16 + lr];
#pragma unroll
    for (int r = 0; r < 4; ++r) {
      float v = acc[r] + bias;
      v = v > 0.f ? v : 0.f;
      int row = w * 16 + q * 4 + r, n = nf * 16 + lr;
      h2s[(row << 7) + (((n >> 3) ^ (row & 7)) << 3) + (n & 7)] = (short)f2bf(v);
    }
  }
  __syncthreads();

  bf16x8 a2[4];
#pragma unroll
  for (int ks = 0; ks < 4; ++ks) {
    int c = ks * 4 + q;
    a2[ks] = *(const bf16x8*)(h2s + (mrow << 7) + ((c ^ (mrow & 7)) << 3));
  }
  const int batch = R0 >> 11;
  const int ib = R0 & 2047;
#pragma unroll
  for (int nf = 0; nf < 8; ++nf) {
    acc = (f32x4){0.f, 0.f, 0.f, 0.f};
#pragma unroll
    for (int ks = 0; ks < 4; ++ks) {
      int c = ks * 4 + q;
      int nr = nf * 16 + lr;
      bf16x8 b = *(const bf16x8*)(w2T + (nr << 7) + ((c ^ (nr & 7)) << 3));
      acc = __builtin_amdgcn_mfma_f32_16x16x32_bf16(a2[ks], b, acc, 0, 0, 0);
    }
    float bias = gb2[nf * 16 + lr];
    u16x4 pk;
#pragma unroll
    for (int r = 0; r < 4; ++r) pk[r] = f2bf(acc[r] + bias);
    *(u16x4*)(gxT + (size_t)(batch * 128 + nf * 16 + lr) * 2048 + ib + w * 16 + q * 4) = pk;
  }
}

// ---------------- k_main: fused einsum + self-MLP ----------------
__device__ __forceinline__ void load_tiles(const float* ep, const unsigned short* gp,
                                           f32x8& er, u16x8 gr[4])
{
  er = *(const f32x8*)ep;
#pragma unroll
  for (int qq = 0; qq < 4; ++qq)
    gr[qq] = *(const u16x8*)(gp + (size_t)qq * 32 * 2048);
}

__global__ __launch_bounds__(256) void k_main(
    const float* __restrict__ edge,
    const unsigned short* __restrict__ gxT,
    const float* __restrict__ x,
    const float* __restrict__ fw1,
    const float* __restrict__ fb1,
    const float* __restrict__ fw2,
    const float* __restrict__ fb2,
    float* __restrict__ out)
{
  // eT[jj 0..31][ii 0..63]: stride 72 shorts, chunk swizzle (ii>>3)^(jj>>3):
  //   addr = jj*72 + (((ii>>3)^(jj>>3))<<3) + (ii&7)
  //   writes: 16 banks x 2-way (free); b128 reads: balanced via odd stride.
  // bT[h 0..127][ii 0..63]: tight XOR: addr = h*64 + (((ii>>3)^(h&7))<<3) + (ii&7)
  __shared__ short eT[32 * 72];    // 4.5 KB
  __shared__ short bT[128 * 64];   // 16 KB (main: gx tile; epilogue: fw2T)
  __shared__ short xs[32 * 64];    // 4 KB  (epilogue)
  __shared__ short w1T[64 * 64];   // 8 KB  (epilogue)
  __shared__ short h1s[32 * 64];   // 4 KB  (epilogue)   total 36.5 KB

  const int t = threadIdx.x;
  const int batch = blockIdx.x & 7;   // XCD-pinned: each XCD sees one batch's gx (512 KB, L2-resident)
  const int j0 = (blockIdx.x >> 3) * 32;

  const int w = t >> 6, l = t & 63;
  const int wm = w & 1, wn = w >> 1;
  const int lr = l & 15, q = l >> 4;

  // loader roles
  const int e_ii = t >> 2;          // 0..63
  const int e_cj = t & 3;           // 0..3  (8 j each)
  const int g_hh = t >> 3;          // 0..31
  const int g_ci = t & 7;           // 0..7  (8 i each)

  const float* ep = edge + (size_t)batch * 2048 * 2048 + (size_t)e_ii * 2048 + j0 + e_cj * 8;
  const unsigned short* gp = gxT + (size_t)batch * 128 * 2048 + (size_t)g_hh * 2048 + g_ci * 8;

  f32x4 acc[4];
#pragma unroll
  for (int nf = 0; nf < 4; ++nf) acc[nf] = (f32x4){0.f, 0.f, 0.f, 0.f};

  f32x8 er;
  u16x8 gr[4];
  load_tiles(ep, gp, er, gr);

  for (int kk = 0; kk < 32; ++kk) {
    __syncthreads();  // prior iter's LDS reads complete
    // edge transpose-store + cvt: 8 scalar u16 per thread
#pragma unroll
    for (int u = 0; u < 8; ++u)
      eT[(e_cj * 8 + u) * 72 + (((e_ii >> 3) ^ e_cj) << 3) + (e_ii & 7)] = (short)f2bf(er[u]);
#pragma unroll
    for (int qq = 0; qq < 4; ++qq) {
      int r = qq * 32 + g_hh;
      *(u16x8*)(bT + (r << 6) + ((g_ci ^ (r & 7)) << 3)) = gr[qq];
    }
    __syncthreads();
    if (kk < 31) {
      ep += 64 * 2048; gp += 64;
      load_tiles(ep, gp, er, gr);   // prefetch overlaps MFMA
    }

#pragma unroll
    for (int ks = 0; ks < 2; ++ks) {
      const int c = ks * 4 + q;
      const int jj = wm * 16 + lr;
      bf16x8 a = *(const bf16x8*)(eT + jj * 72 + ((c ^ (jj >> 3)) << 3));
      bf16x8 b[4];
#pragma unroll
      for (int nf = 0; nf < 4; ++nf) {
        int h = wn * 64 + nf * 16 + lr;
        b[nf] = *(const bf16x8*)(bT + (h << 6) + ((c ^ (h & 7)) << 3));
      }
#pragma unroll
      for (int nf = 0; nf < 4; ++nf)
        acc[nf] = __builtin_amdgcn_mfma_f32_16x16x32_bf16(a, b[nf], acc[nf], 0, 0, 0);
    }
  }

  // ---- fused self-MLP epilogue: acc += relu(x_j @ fw1 + b1) @ fw2 + b2 ----
  __syncthreads();  // done reading bT from main loop
  for (int idx = t; idx < 64 * 64; idx += 256) {
    int k = idx >> 6, n = idx & 63;  // fw1[k][n]
    w1T[(n << 6) + (((k >> 3) ^ (n & 7)) << 3) + (k & 7)] = (short)f2bf(fw1[idx]);
  }
  for (int idx = t; idx < 64 * 128; idx += 256) {
    int k = idx >> 7, n = idx & 127;  // fw2[k][n] -> bT reused as fw2T
    bT[(n << 6) + (((k >> 3) ^ (n & 7)) << 3) + (k & 7)] = (short)f2bf(fw2[idx]);
  }
  for (int s = t; s < 32 * 16; s += 256) {
    int row = s >> 4, c4 = s & 15;
    f32x4 v = *(const f32x4*)(x + (size_t)(batch * 2048 + j0 + row) * 64 + c4 * 4);
    u16x4 pk;
#pragma unroll
    for (int r = 0; r < 4; ++r) pk[r] = f2bf(v[r]);
    *(u16x4*)(xs + (row << 6) + (((c4 >> 1) ^ (row & 7)) << 3) + ((c4 & 1) << 2)) = pk;
  }
  __syncthreads();

  const int mrow = wm * 16 + lr;
  if (wn == 0) {  // layer 1: two waves compute hidden[32][64]
    bf16x8 a1[2];
#pragma unroll
    for (int ks = 0; ks < 2; ++ks) {
      int c = ks * 4 + q;
      a1[ks] = *(const bf16x8*)(xs + (mrow << 6) + ((c ^ (mrow & 7)) << 3));
    }
#pragma unroll
    for (int nf = 0; nf < 4; ++nf) {
      f32x4 h = (f32x4){0.f, 0.f, 0.f, 0.f};
#pragma unroll
      for (int ks = 0; ks < 2; ++ks) {
        int c = ks * 4 + q;
        int nr = nf * 16 + lr;
        bf16x8 b = *(const bf16x8*)(w1T + (nr << 6) + ((c ^ (nr & 7)) << 3));
        h = __builtin_amdgcn_mfma_f32_16x16x32_bf16(a1[ks], b, h, 0, 0, 0);
      }
      float bias = fb1[nf * 16 + lr];
#pragma unroll
      for (int r = 0; r < 4; ++r) {
        float v = h[r] + bias;
        v = v > 0.f ? v : 0.f;
        int row = wm * 16 + q * 4 + r, n = nf * 16 + lr;
        h1s[(row << 6) + (((n >> 3) ^ (row & 7)) << 3) + (n & 7)] = (short)f2bf(v);
      }
    }
  }
  __syncthreads();

  // layer 2: all waves, accumulate straight into einsum acc
  bf16x8 a2[2];
#pragma unroll
  for (int ks = 0; ks < 2; ++ks) {
    int c = ks * 4 + q;
    a2[ks] = *(const bf16x8*)(h1s + (mrow << 6) + ((c ^ (mrow & 7)) << 3));
  }
#pragma unroll
  for (int nf = 0; nf < 4; ++nf) {
    int h = wn * 64 + nf * 16 + lr;
#pragma unroll
    for (int ks = 0; ks < 2; ++ks) {
      int c = ks * 4 + q;
      bf16x8 b = *(const bf16x8*)(bT + (h << 6) + ((c ^ (h & 7)) << 3));
      acc[nf] = __builtin_amdgcn_mfma_f32_16x16x32_bf16(a2[ks], b, acc[nf], 0, 0, 0);
    }
    float bias = fb2[h];
#pragma unroll
    for (int r = 0; r < 4; ++r) {
      size_t o = ((size_t)batch * 2048 + j0 + wm * 16 + q * 4 + r) * 128 + h;
      out[o] = acc[nf][r] + bias;
    }
  }
}

extern "C" void kernel_launch(void* const* d_in, const int* in_sizes, int n_in,
                              void* d_out, int out_size, void* d_ws, size_t ws_size,
                              hipStream_t stream) {
  const float* x    = (const float*)d_in[0];
  const float* edge = (const float*)d_in[1];
  const float* fw1  = (const float*)d_in[2];
  const float* fb1  = (const float*)d_in[3];
  const float* fw2  = (const float*)d_in[4];
  const float* fb2  = (const float*)d_in[5];
  const float* gw1  = (const float*)d_in[6];
  const float* gb1  = (const float*)d_in[7];
  const float* gw2  = (const float*)d_in[8];
  const float* gb2  = (const float*)d_in[9];
  float* out = (float*)d_out;

  unsigned short* gxT = (unsigned short*)d_ws;  // [8][128][2048] bf16, 4 MB

  hipLaunchKernelGGL(k_gx, dim3(256), dim3(256), 0, stream, x, gw1, gb1, gw2, gb2, gxT);
  hipLaunchKernelGGL(k_main, dim3(512), dim3(256), 0, stream, edge, gxT, x,
                     fw1, fb1, fw2, fb2, out);
}